// Round 3
// baseline (196.718 us; speedup 1.0000x reference)
//
#include <hip/hip_runtime.h>
#include <hip/hip_bf16.h>

// ALiBi attention, B=8 L=1024 H=8 E=64, fp32 in/out, bf16 MFMA inside.
// Outputs: V [B,L,H,E] then series [B,H,L,L] concatenated in d_out.
// Two-pass, fixed-max softmax (M=32 in log2 domain), all LDS XOR-swizzled,
// P written back coalesced from LDS. XCD-aware block mapping.

typedef short short8 __attribute__((ext_vector_type(8)));
typedef float f32x4 __attribute__((ext_vector_type(4)));
typedef unsigned short u16x4 __attribute__((ext_vector_type(4)));

#define B_ 8
#define L_ 1024
#define H_ 8
#define E_ 64
#define QBLK 64    // 4 waves x 16 rows
#define CHUNK 64   // keys per chunk
#define NCH (L_ / CHUNK)

__device__ __forceinline__ unsigned short f2bf(float f) {
  return __builtin_bit_cast(unsigned short, __float2bfloat16(f));
}
__device__ __forceinline__ float bf2f(unsigned short u) {
  return __builtin_bit_cast(float, (unsigned int)u << 16);
}

__global__ __launch_bounds__(256, 6) void alibi_attn(
    const float* __restrict__ Qg, const float* __restrict__ Kg,
    const float* __restrict__ Vg, float* __restrict__ Vout,
    float* __restrict__ Pout) {
  // all tiles: row stride 64 ushorts (128B); 16B groups XOR-swizzled by row&7
  __shared__ unsigned short sK[CHUNK * 64];  // [s][e]
  __shared__ unsigned short sVT[E_ * 64];    // [e][s]
  __shared__ unsigned short sP[4][16 * 64];  // per-wave [row][c]

  const int t = threadIdx.x;
  const int lane = t & 63;
  const int w = t >> 6;
  const int col = lane & 15;
  const int kg = lane >> 4;

  // XCD-aware decode: same-(b,h) blocks share id%8 -> same XCD -> K/V L2-hot
  const int id = blockIdx.x;
  const int qb = id >> 6;
  const int bh = id & 63;
  const int h = bh & 7;
  const int b = bh >> 3;
  const int q0 = qb * QBLK;

  const float L2E = 1.44269504f;
  const float sc_l2e = 0.125f * L2E;                    // scale*log2e
  const float sl_l2e = exp2f(-(float)(h + 1) * 0.125f) * L2E;

  // ---- Q fragments (A-frag): row=lane&15, k=8*kg+j+32*ks ----
  short8 qf[2];
  {
    const float* qp =
        &Qg[(((size_t)b * L_ + q0 + 16 * w + col) * H_ + h) * E_ + 8 * kg];
#pragma unroll
    for (int ks = 0; ks < 2; ++ks) {
      float4 a0 = *reinterpret_cast<const float4*>(qp + 32 * ks);
      float4 a1 = *reinterpret_cast<const float4*>(qp + 32 * ks + 4);
      qf[ks] = (short8){(short)f2bf(a0.x), (short)f2bf(a0.y), (short)f2bf(a0.z),
                        (short)f2bf(a0.w), (short)f2bf(a1.x), (short)f2bf(a1.y),
                        (short)f2bf(a1.z), (short)f2bf(a1.w)};
    }
  }

  float z_[4] = {0.f, 0.f, 0.f, 0.f};

  // ======== Pass A: z = sum exp2(u - 32), fixed max ========
  for (int c = 0; c < NCH; ++c) {
    const int kv0 = c * CHUNK;
    __syncthreads();
    {  // stage K chunk (swizzled)
      const int e = 4 * (t & 15);
      const int srow = t >> 4;
#pragma unroll
      for (int it = 0; it < 4; ++it) {
        const int s = srow + 16 * it;
        float4 v = *reinterpret_cast<const float4*>(
            &Kg[(((size_t)b * L_ + kv0 + s) * H_ + h) * E_ + e]);
        *reinterpret_cast<u16x4*>(
            &sK[s * 64 + (((e >> 3) ^ (s & 7)) << 3) + (e & 7)]) =
            (u16x4){f2bf(v.x), f2bf(v.y), f2bf(v.z), f2bf(v.w)};
      }
    }
    __syncthreads();
#pragma unroll
    for (int kt = 0; kt < 4; ++kt) {
      f32x4 acc = {0.f, 0.f, 0.f, 0.f};
      const int krow = 16 * kt + col;
#pragma unroll
      for (int ks = 0; ks < 2; ++ks) {
        short8 kf = *reinterpret_cast<const short8*>(
            &sK[krow * 64 + (((4 * ks + kg) ^ (krow & 7)) << 3)]);
        acc = __builtin_amdgcn_mfma_f32_16x16x32_bf16(qf[ks], kf, acc, 0, 0, 0);
      }
      const float vb = sl_l2e * (float)(kv0 + krow - (L_ - 1)) - 32.0f;
#pragma unroll
      for (int r = 0; r < 4; ++r) z_[r] += exp2f(acc[r] * sc_l2e + vb);
    }
  }

  // combine z across the 16 lanes sharing each row
  float minv_[4];
#pragma unroll
  for (int r = 0; r < 4; ++r) {
    float z = z_[r];
#pragma unroll
    for (int off = 1; off < 16; off <<= 1) z += __shfl_xor(z, off, 64);
    minv_[r] = 1.0f / z;
  }

  // ======== Pass B: recompute S, P->LDS, PV, coalesced P writeback ========
  f32x4 oacc[4];
#pragma unroll
  for (int et = 0; et < 4; ++et) oacc[et] = (f32x4){0.f, 0.f, 0.f, 0.f};

  unsigned short* sPw = &sP[w][0];
  float* Pb = Pout + (((size_t)(b * H_ + h) * L_) + q0 + 16 * w) * L_;

  for (int c = 0; c < NCH; ++c) {
    const int kv0 = c * CHUNK;
    __syncthreads();
    {  // stage K chunk
      const int e = 4 * (t & 15);
      const int srow = t >> 4;
#pragma unroll
      for (int it = 0; it < 4; ++it) {
        const int s = srow + 16 * it;
        float4 v = *reinterpret_cast<const float4*>(
            &Kg[(((size_t)b * L_ + kv0 + s) * H_ + h) * E_ + e]);
        *reinterpret_cast<u16x4*>(
            &sK[s * 64 + (((e >> 3) ^ (s & 7)) << 3) + (e & 7)]) =
            (u16x4){f2bf(v.x), f2bf(v.y), f2bf(v.z), f2bf(v.w)};
      }
    }
    {  // stage V^T chunk (swizzled): lane owns one e, 4 s per iter
      const int e = lane;
#pragma unroll
      for (int i = 0; i < 4; ++i) {
        const int s4 = 4 * w + 16 * i;
        const float* vp = &Vg[(((size_t)b * L_ + kv0 + s4) * H_ + h) * E_ + e];
        float x0 = vp[0];
        float x1 = vp[H_ * E_];
        float x2 = vp[2 * H_ * E_];
        float x3 = vp[3 * H_ * E_];
        *reinterpret_cast<u16x4*>(
            &sVT[e * 64 + (((s4 >> 3) ^ (e & 7)) << 3) + (s4 & 7)]) =
            (u16x4){f2bf(x0), f2bf(x1), f2bf(x2), f2bf(x3)};
      }
    }
    __syncthreads();

    // QK^T, emit P (bf16) into wave-private sP
#pragma unroll
    for (int kt = 0; kt < 4; ++kt) {
      f32x4 acc = {0.f, 0.f, 0.f, 0.f};
      const int krow = 16 * kt + col;
#pragma unroll
      for (int ks = 0; ks < 2; ++ks) {
        short8 kf = *reinterpret_cast<const short8*>(
            &sK[krow * 64 + (((4 * ks + kg) ^ (krow & 7)) << 3)]);
        acc = __builtin_amdgcn_mfma_f32_16x16x32_bf16(qf[ks], kf, acc, 0, 0, 0);
      }
      const float vb = sl_l2e * (float)(kv0 + krow - (L_ - 1)) - 32.0f;
#pragma unroll
      for (int r = 0; r < 4; ++r) {
        const float pf = exp2f(acc[r] * sc_l2e + vb) * minv_[r];
        const int row = 4 * kg + r;
        sPw[row * 64 + ((((16 * kt + col) >> 3) ^ (row & 7)) << 3) + (col & 7)] =
            f2bf(pf);
      }
    }

    // PV: O += P * V (wave-private sP, freshly staged sVT)
#pragma unroll
    for (int ks = 0; ks < 2; ++ks) {
      short8 af = *reinterpret_cast<const short8*>(
          &sPw[col * 64 + (((4 * ks + kg) ^ (col & 7)) << 3)]);
#pragma unroll
      for (int et = 0; et < 4; ++et) {
        const int er = 16 * et + col;
        short8 vf = *reinterpret_cast<const short8*>(
            &sVT[er * 64 + (((4 * ks + kg) ^ (er & 7)) << 3)]);
        oacc[et] =
            __builtin_amdgcn_mfma_f32_16x16x32_bf16(af, vf, oacc[et], 0, 0, 0);
      }
    }

    // coalesced P writeback: wave writes its own 16x64 tile as float4 rows
#pragma unroll
    for (int i = 0; i < 4; ++i) {
      const int f = i * 64 + lane;
      const int row = f >> 4;
      const int c0 = 4 * (f & 15);
      u16x4 u = *reinterpret_cast<const u16x4*>(
          &sPw[row * 64 + (((c0 >> 3) ^ (row & 7)) << 3) + (c0 & 7)]);
      f32x4 o = {bf2f(u[0]), bf2f(u[1]), bf2f(u[2]), bf2f(u[3])};
      __builtin_nontemporal_store(
          o, reinterpret_cast<f32x4*>(&Pb[(size_t)row * L_ + kv0 + c0]));
    }
  }

  // ---- write O ----
  float* Vb = Vout + (((size_t)b * L_ + q0 + 16 * w) * H_ + h) * E_;
#pragma unroll
  for (int et = 0; et < 4; ++et) {
#pragma unroll
    for (int r = 0; r < 4; ++r) {
      __builtin_nontemporal_store(oacc[et][r],
                                  &Vb[(4 * kg + r) * H_ * E_ + 16 * et + col]);
    }
  }
}

extern "C" void kernel_launch(void* const* d_in, const int* in_sizes, int n_in,
                              void* d_out, int out_size, void* d_ws,
                              size_t ws_size, hipStream_t stream) {
  const float* Q = (const float*)d_in[0];
  const float* K = (const float*)d_in[1];
  const float* V = (const float*)d_in[2];
  float* out = (float*)d_out;
  float* Vo = out;                              // [B,L,H,E]
  float* Po = out + (size_t)B_ * L_ * H_ * E_;  // [B,H,L,L]
  hipLaunchKernelGGL(alibi_attn, dim3((L_ / QBLK) * H_ * B_), dim3(256), 0,
                     stream, Q, K, V, Vo, Po);
}